// Round 5
// baseline (10822.649 us; speedup 1.0000x reference)
//
#include <hip/hip_runtime.h>
#include <math.h>

#define NB 64
#define NT 1024
#define NI 128
#define NH 512

typedef unsigned long long u64;

// ---------------------------------------------------------------------------
// prep: transpose input-proj weights to k-major [k][j*4+m]; init tagged h
// buffers (staging + shadow, both parities, contiguous): tag=0, value=1.0f.
// Visible to phase2 via end-of-kernel cache writeback (stream order).
// ---------------------------------------------------------------------------
__global__ __launch_bounds__(256) void prep_kernel(
    const float* __restrict__ Wsw, const float* __restrict__ Wsm,
    const float* __restrict__ Wss, const float* __restrict__ Wtcx,
    float* __restrict__ WT_in, u64* __restrict__ htag)
{
  int idx = blockIdx.x * blockDim.x + threadIdx.x;
  int np  = gridDim.x * blockDim.x;
  for (int i = idx; i < NH * NI; i += np) {
    int j = i >> 7, k = i & 127;            // W is [H][I] row-major
    int o = k * 2048 + j * 4;
    WT_in[o + 0] = Wsw[i];
    WT_in[o + 1] = Wsm[i];
    WT_in[o + 2] = Wss[i];
    WT_in[o + 3] = Wtcx[i];
  }
  // staging[2 parities] + shadow[2 parities], contiguous
  for (int i = idx; i < 4 * NB * NH; i += np) htag[i] = 0x3F800000ULL;
}

// ---------------------------------------------------------------------------
// phase1: sensory + tcx for all (b,t).  Block = 32 rows x all 512 j.
// ---------------------------------------------------------------------------
__global__ __launch_bounds__(256, 2) void phase1_kernel(
    const float* __restrict__ x, const float* __restrict__ WT_in,
    const float* __restrict__ bsw, const float* __restrict__ bsm,
    const float* __restrict__ bss, const float* __restrict__ btc,
    float* __restrict__ sens, float* __restrict__ tcx)
{
  __shared__ __align__(16) float xs[32 * NI];   // 16 KB
  const int tid = threadIdx.x;
  const int n0  = blockIdx.x * 32;

  const float4* xsrc = (const float4*)(x + (size_t)n0 * NI);
#pragma unroll
  for (int i = 0; i < 4; i++)
    ((float4*)xs)[i * 256 + tid] = xsrc[i * 256 + tid];
  __syncthreads();

  for (int jj = 0; jj < 2; jj++) {
    const int j = tid + jj * 256;
    float4 acc[32];
#pragma unroll
    for (int n = 0; n < 32; n++) acc[n] = make_float4(0.f, 0.f, 0.f, 0.f);

    const float4* wp = (const float4*)WT_in + j;   // row k at wp[k*512]
#pragma unroll 2
    for (int k = 0; k < NI; k++) {
      float4 w = wp[(size_t)k * 512];
#pragma unroll
      for (int n = 0; n < 32; n++) {
        float xv = xs[n * NI + k];
        acc[n].x = fmaf(xv, w.x, acc[n].x);
        acc[n].y = fmaf(xv, w.y, acc[n].y);
        acc[n].z = fmaf(xv, w.z, acc[n].z);
        acc[n].w = fmaf(xv, w.w, acc[n].w);
      }
    }
    const float b0 = bsw[j], b1 = bsm[j], b2v = bss[j], b3 = btc[j];
#pragma unroll 4
    for (int n = 0; n < 32; n++) {
      float sw = acc[n].x + b0;
      float sm = acc[n].y + b1;
      float ss = acc[n].z + b2v;
      float tc = acc[n].w + b3;
      float sig = 1.f / (1.f + expf(-sm));
      float se  = expf(fminf(ss, 50.f));
      size_t o = (size_t)(n0 + n) * NH + j;
      sens[o] = sw * sig * se;
      tcx[o]  = tc;
    }
  }
}

// ---------------------------------------------------------------------------
// 16 tagged-word gather through the XCD L2 (sc0 = bypass L1, serve from
// L2).  Fully-VGPR 64-bit addressing: 4 address pairs spaced 8192 B, each
// covering 4 rows via the 13-bit signed offset {-4096,-2048,0,+2048}.
// All loads + the vmcnt drain live in ONE asm so in-flight dest regs have
// no compiler-visible spill window.
// ---------------------------------------------------------------------------
#define GATHER16(W, A0, A1, A2, A3)                                        \
  asm volatile(                                                            \
      "global_load_dwordx2 %[w0],  %[a0], off offset:-4096 sc0\n\t"        \
      "global_load_dwordx2 %[w1],  %[a0], off offset:-2048 sc0\n\t"        \
      "global_load_dwordx2 %[w2],  %[a0], off sc0\n\t"                     \
      "global_load_dwordx2 %[w3],  %[a0], off offset:2048 sc0\n\t"         \
      "global_load_dwordx2 %[w4],  %[a1], off offset:-4096 sc0\n\t"        \
      "global_load_dwordx2 %[w5],  %[a1], off offset:-2048 sc0\n\t"        \
      "global_load_dwordx2 %[w6],  %[a1], off sc0\n\t"                     \
      "global_load_dwordx2 %[w7],  %[a1], off offset:2048 sc0\n\t"         \
      "global_load_dwordx2 %[w8],  %[a2], off offset:-4096 sc0\n\t"        \
      "global_load_dwordx2 %[w9],  %[a2], off offset:-2048 sc0\n\t"        \
      "global_load_dwordx2 %[w10], %[a2], off sc0\n\t"                     \
      "global_load_dwordx2 %[w11], %[a2], off offset:2048 sc0\n\t"         \
      "global_load_dwordx2 %[w12], %[a3], off offset:-4096 sc0\n\t"        \
      "global_load_dwordx2 %[w13], %[a3], off offset:-2048 sc0\n\t"        \
      "global_load_dwordx2 %[w14], %[a3], off sc0\n\t"                     \
      "global_load_dwordx2 %[w15], %[a3], off offset:2048 sc0\n\t"         \
      "s_waitcnt vmcnt(0)"                                                 \
      : [w0] "=&v"(W[0]), [w1] "=&v"(W[1]), [w2] "=&v"(W[2]),              \
        [w3] "=&v"(W[3]), [w4] "=&v"(W[4]), [w5] "=&v"(W[5]),              \
        [w6] "=&v"(W[6]), [w7] "=&v"(W[7]), [w8] "=&v"(W[8]),              \
        [w9] "=&v"(W[9]), [w10] "=&v"(W[10]), [w11] "=&v"(W[11]),          \
        [w12] "=&v"(W[12]), [w13] "=&v"(W[13]), [w14] "=&v"(W[14]),        \
        [w15] "=&v"(W[15])                                                 \
      : [a0] "v"(A0), [a1] "v"(A1), [a2] "v"(A2), [a3] "v"(A3)             \
      : "memory")

// ---------------------------------------------------------------------------
// phase2: persistent recurrent scan.  Round-0 compute structure (256 thr,
// 1 wave/SIMD, VGPR weights, skewed LDS, acc[4][8]) with the h exchange
// moved onto the PER-XCD L2:
//
// Rounds 0/2/3 all distributed h via per-lane 8B agent-scope (MALL)
// transactions: 512K uncached 8B ops per step (4 MB, 32x redundant).
// That uncached-path throughput is the invariant ~15k-cycle floor (round
// 3 killed poll volume AND detection cost; step time moved 4%).
//
// bg = blockIdx&7 coincides with the round-robin XCD heuristic, so all 32
// blocks of a clique share ONE XCD and its L2 = their coherence point:
//   - writers publish tagged {t+1, h} words twice: PLAIN cached store to a
//     staging buffer (write-through L0 -> lands in local XCD L2) + relaxed
//     agent-scope atomic to a shadow buffer (MALL; the proven fallback).
//   - readers gather staging via `global_load_dwordx2 ... sc0` (bypass L1,
//     SERVE FROM L2): ~200cy, line-granule BW.  Tags gate every word; a
//     word still stale after FASTR fast rounds escalates per-word to the
//     shadow path.  (Round 2's `volatile` compiled to cache-BYPASSING ops
//     -- an HBM path.  sc0 via asm is the actual L2 path.)
// Correctness is placement-independent: tags self-validate, the shadow
// path alone is the round-0 protocol, and the round-0 dependency argument
// (publishing tag t+1 data-depends on ALL tag-t reads) makes the parity
// double-buffer race-free with no fences/counters/drains.  Wrong placement
// merely degrades to ~round-0 speed (stale local-L2 lines never validate,
// FASTR wasted rounds, then the shadow path completes the step).
// ---------------------------------------------------------------------------
__global__ __launch_bounds__(256, 1) void phase2_kernel(
    const float* __restrict__ Wiw, const float* __restrict__ Wim,
    const float* __restrict__ Wis, const float* __restrict__ Wtch,
    const float* __restrict__ biw, const float* __restrict__ bim,
    const float* __restrict__ bis,
    const float* __restrict__ tcx, float* __restrict__ out,
    u64* __restrict__ hstage, u64* __restrict__ hshad)
{
  __shared__ __align__(16) float hl[8 * 576];   // skewed h tile
  __shared__ float red[4 * 528];                // reduction scratch

  const int tid = threadIdx.x;
  const int wv  = tid >> 6;
  const int ln  = tid & 63;
  const int bg  = blockIdx.x & 7;
  const int js  = blockIdx.x >> 3;

  const int cg = ln & 15;
  const int r  = wv * 4 + (ln >> 4);   // k-range id 0..15
  const int k0 = r << 5;

  // persistent weights (128 VGPRs): col c = cg + 16*ci, gate g = cg&3
  const int g   = cg & 3;
  const int jl0 = cg >> 2;
  const float* Wp = (g == 0) ? Wiw : (g == 1) ? Wim : (g == 2) ? Wis : Wtch;
  float wreg[4][32];
#pragma unroll
  for (int ci = 0; ci < 4; ci++) {
    const float* wrow = Wp + (size_t)(js * 16 + jl0 + 4 * ci) * NH + k0;
#pragma unroll
    for (int kk = 0; kk < 32; kk++) wreg[ci][kk] = wrow[kk];
  }

  // epilogue-thread constants (tid<128 handles (b = tid>>4, jl = tid&15))
  const int ejl = tid & 15;
  const int eb  = tid >> 4;
  const int ej  = js * 16 + ejl;
  float bw = 0.f, bm = 0.f, bs = 0.f;
  if (tid < 128) { bw = biw[ej]; bm = bim[ej]; bs = bis[ej]; }

  u64* const sg0 = hstage + bg * 4096;            // staging, parity 0
  u64* const sg1 = hstage + NB * NH + bg * 4096;  // staging, parity 1
  u64* const sh0 = hshad + bg * 4096;             // shadow, parity 0
  u64* const sh1 = hshad + NB * NH + bg * 4096;   // shadow, parity 1

  // VGPR 64-bit gather bases (center-of-4-rows + 4096 for signed offsets)
  const u64 gb0 = (u64)(uintptr_t)sg0 + (u64)(tid * 8) + 4096;
  const u64 gb1 = (u64)(uintptr_t)sg1 + (u64)(tid * 8) + 4096;

  const int FASTR = 8;   // fast (L2) rounds before per-word MALL escalation

  for (int t = 0; t < NT; t++) {
    u64* msrc = (t & 1) ? sh1 : sh0;
    u64* sdst = (t & 1) ? sg0 : sg1;
    u64* mdst = (t & 1) ? sh0 : sh1;
    const u64 gb = (t & 1) ? gb1 : gb0;
    const u64 gA1 = gb + 8192, gA2 = gb + 16384, gA3 = gb + 24576;
    const unsigned want = (unsigned)t;

    // ---- tagged gather of h(t) through the XCD L2 ----
    u64 w[16];
    GATHER16(w, gb, gA1, gA2, gA3);
    int rnd = 0;
    for (;;) {
      bool ok = true;
#pragma unroll
      for (int i = 0; i < 16; i++) ok = ok && ((unsigned)(w[i] >> 32) == want);
      if (ok) break;
      ++rnd;
      if (rnd <= FASTR) {
        GATHER16(w, gb, gA1, gA2, gA3);   // L2-served; BW self-throttles
      } else {
        __builtin_amdgcn_s_sleep(1);
#pragma unroll
        for (int i = 0; i < 16; i++)
          if ((unsigned)(w[i] >> 32) != want)
            w[i] = __hip_atomic_load(msrc + i * 256 + tid, __ATOMIC_RELAXED,
                                     __HIP_MEMORY_SCOPE_AGENT);
      }
    }

    // ---- prefetch sens/tcx (HBM; hidden under scatter+dot) ----
    float sens_v = 0.f, tcx_v = 0.f;
    size_t eidx = 0;
    if (tid < 128) {
      eidx   = ((size_t)(bg * 8 + eb) * NT + t) * NH + ej;
      sens_v = out[eidx];
      tcx_v  = tcx[eidx];
    }

    // ---- scatter to skewed LDS tile ----
#pragma unroll
    for (int i = 0; i < 16; i++) {
      int f  = i * 256 + tid;
      int b2 = f >> 9, k = f & 511;
      hl[b2 * 576 + (k >> 5) * 36 + (k & 31)] =
          __uint_as_float((unsigned)(w[i] & 0xFFFFFFFFull));
    }
    __syncthreads();   // (A) tile visible; also protects red[] across steps

    // ---- partial dots: 4 cols x 8 batches over 32 k ----
    float acc[4][8];
#pragma unroll
    for (int ci = 0; ci < 4; ci++)
#pragma unroll
      for (int b2 = 0; b2 < 8; b2++) acc[ci][b2] = 0.f;

    const float* hb = hl + r * 36;
#pragma unroll
    for (int b2 = 0; b2 < 8; b2++) {
#pragma unroll
      for (int kc = 0; kc < 32; kc += 4) {
        float4 hv = *(const float4*)(hb + b2 * 576 + kc);
#pragma unroll
        for (int ci = 0; ci < 4; ci++) {
          acc[ci][b2] = fmaf(wreg[ci][kc + 0], hv.x, acc[ci][b2]);
          acc[ci][b2] = fmaf(wreg[ci][kc + 1], hv.y, acc[ci][b2]);
          acc[ci][b2] = fmaf(wreg[ci][kc + 2], hv.z, acc[ci][b2]);
          acc[ci][b2] = fmaf(wreg[ci][kc + 3], hv.w, acc[ci][b2]);
        }
      }
    }

    // ---- reduce over 16 k-ranges ----
#pragma unroll
    for (int ci = 0; ci < 4; ci++)
#pragma unroll
      for (int b2 = 0; b2 < 8; b2++) {
        float v = acc[ci][b2];
        v += __shfl_xor(v, 16, 64);
        v += __shfl_xor(v, 32, 64);
        acc[ci][b2] = v;
      }
    if (ln < 16) {
#pragma unroll
      for (int ci = 0; ci < 4; ci++)
#pragma unroll
        for (int b2 = 0; b2 < 8; b2++)
          red[wv * 528 + ln * 33 + ci * 8 + b2] = acc[ci][b2];
    }
    // h_old read BEFORE barrier (B): hl stays untouched until after (B)
    float h_old = 0.f;
    if (tid < 128) h_old = hl[eb * 576 + (ej >> 5) * 36 + (ej & 31)];
    __syncthreads();   // (B) red visible

    // ---- epilogue: 128 (b,j) pairs ----
    if (tid < 128) {
      float vals[4];
#pragma unroll
      for (int g2 = 0; g2 < 4; g2++) {
        int c = ejl * 4 + g2;
        int o = (c & 15) * 33 + (c >> 4) * 8 + eb;
        vals[g2] = red[o] + red[528 + o] + red[1056 + o] + red[1584 + o];
      }
      float iwv = vals[0] + bw;
      float imv = vals[1] + bm;
      float isv = vals[2] + bs;
      float tch = vals[3];
      float z   = tcx_v + tch;
      float tau = fmaxf(z, 0.f) + log1pf(expf(-fabsf(z))) + 0.1f;  // softplus+0.1
      float sig = 1.f / (1.f + expf(-imv));
      float inter = iwv * sig * expf(fminf(isv, 50.f));
      float dh  = (sens_v + inter - h_old) / fmaxf(tau, 1e-8f);
      float hnew = h_old + 0.1f * dh;
      u64 nw = ((u64)(unsigned)(t + 1) << 32) | (u64)__float_as_uint(hnew);
      // dual publish: plain cached store (this XCD's L2, the fast path)...
      sdst[eb * 512 + ej] = nw;
      // ...then the placement-independent MALL copy (fallback path)
      __hip_atomic_store(mdst + eb * 512 + ej, nw, __ATOMIC_RELAXED,
                         __HIP_MEMORY_SCOPE_AGENT);
      out[eidx] = hnew;                              // overwrite sens in place
    }
    // no end-of-step barrier: next scatter's hl writes happen only after
    // that wave passes (B), and all hl/red reads precede (B).
  }
}

// ---------------------------------------------------------------------------
extern "C" void kernel_launch(void* const* d_in, const int* in_sizes, int n_in,
                              void* d_out, int out_size, void* d_ws, size_t ws_size,
                              hipStream_t stream) {
  const float* x    = (const float*)d_in[0];
  const float* Wsw  = (const float*)d_in[1];
  const float* bsw  = (const float*)d_in[2];
  const float* Wsm  = (const float*)d_in[3];
  const float* bsm  = (const float*)d_in[4];
  const float* Wss  = (const float*)d_in[5];
  const float* bss  = (const float*)d_in[6];
  const float* Wiw  = (const float*)d_in[7];
  const float* biw  = (const float*)d_in[8];
  const float* Wim  = (const float*)d_in[9];
  const float* bim  = (const float*)d_in[10];
  const float* Wis  = (const float*)d_in[11];
  const float* bis  = (const float*)d_in[12];
  const float* Wtcx = (const float*)d_in[13];
  const float* Wtch = (const float*)d_in[14];
  const float* btc  = (const float*)d_in[15];
  float* out = (float*)d_out;

  // workspace (floats): WT_in[128*2048] | tcx[B*T*H] |
  //                     hstage[2*B*H u64] | hshad[2*B*H u64]
  float* ws     = (float*)d_ws;
  float* WT_in  = ws;
  float* tcx    = ws + 262144;
  u64*   hstage = (u64*)(tcx + (size_t)NB * NT * NH);
  u64*   hshad  = hstage + 2 * NB * NH;

  hipLaunchKernelGGL(prep_kernel, dim3(256), dim3(256), 0, stream,
                     Wsw, Wsm, Wss, Wtcx, WT_in, hstage);

  hipLaunchKernelGGL(phase1_kernel, dim3(NB * NT / 32), dim3(256), 0, stream,
                     x, WT_in, bsw, bsm, bss, btc, out, tcx);

  hipLaunchKernelGGL(phase2_kernel, dim3(256), dim3(256), 0, stream,
                     Wiw, Wim, Wis, Wtch, biw, bim, bis,
                     tcx, out, hstage, hshad);
}